// Round 1
// baseline (426.375 us; speedup 1.0000x reference)
//
#include <hip/hip_runtime.h>
#include <hip/hip_bf16.h>
#include <math.h>

#define NTOK 4096
#define DIMSZ 1024
#define HID 4096
#define NE 8
#define RT_MAX 40   // max sum over experts of ceil(count/128) is 39; pad to 40

typedef unsigned short u16;
typedef unsigned int u32;
typedef __attribute__((ext_vector_type(8))) short bf16x8;
typedef __attribute__((ext_vector_type(4))) float f32x4;

static __device__ __forceinline__ u16 f2bf(float f) {
    u32 u = __float_as_uint(f);
    u32 r = u + 0x7fffu + ((u >> 16) & 1u);   // round-to-nearest-even
    return (u16)(r >> 16);
}

// ---------------- init: zero counts + cursor ----------------
__global__ void k_init(int* counts, int* cursor) {
    if (threadIdx.x < NE) { counts[threadIdx.x] = 0; cursor[threadIdx.x] = 0; }
}

// ---------------- router: fp32 argmax over 8 experts ----------------
__global__ __launch_bounds__(256) void k_router(const float* __restrict__ x,
                                                const float* __restrict__ Wg,
                                                int* __restrict__ ids,
                                                int* __restrict__ counts) {
    int wave = threadIdx.x >> 6;
    int lane = threadIdx.x & 63;
    int t = blockIdx.x * 4 + wave;

    const float4* xr = (const float4*)(x + (size_t)t * DIMSZ);
    float4 xv[4];
#pragma unroll
    for (int j = 0; j < 4; j++) xv[j] = xr[j * 64 + lane];

    float s[NE];
#pragma unroll
    for (int e = 0; e < NE; e++) {
        const float4* wr = (const float4*)(Wg + (size_t)e * DIMSZ);
        float p = 0.f;
#pragma unroll
        for (int j = 0; j < 4; j++) {
            float4 w = wr[j * 64 + lane];
            p += xv[j].x * w.x + xv[j].y * w.y + xv[j].z * w.z + xv[j].w * w.w;
        }
#pragma unroll
        for (int m = 32; m >= 1; m >>= 1) p += __shfl_xor(p, m, 64);
        s[e] = p;
    }
    if (lane == 0) {
        int best = 0;
#pragma unroll
        for (int e = 1; e < NE; e++) if (s[e] > s[best]) best = e;  // first-max tiebreak
        ids[t] = best;
        atomicAdd(&counts[best], 1);
    }
}

// ---------------- scan: exclusive prefix over 8 counts ----------------
__global__ void k_scan(const int* __restrict__ counts, int* __restrict__ offs) {
    if (threadIdx.x == 0) {
        int a = 0;
        for (int e = 0; e < NE; e++) { offs[e] = a; a += counts[e]; }
    }
}

// ---------------- gather: build perm + bf16-convert x into grouped Xg ----------------
__global__ __launch_bounds__(256) void k_gather(const float* __restrict__ x,
                                                const int* __restrict__ ids,
                                                const int* __restrict__ offs,
                                                int* __restrict__ cursor,
                                                int* __restrict__ perm,
                                                u16* __restrict__ Xg) {
    int t = blockIdx.x;
    __shared__ int sp;
    if (threadIdx.x == 0) {
        int e = ids[t];
        int p = offs[e] + atomicAdd(&cursor[e], 1);
        perm[p] = t;
        sp = p;
    }
    __syncthreads();
    int p = sp;
    const float4* src = (const float4*)(x + (size_t)t * DIMSZ);
    float4 v = src[threadIdx.x];
    u32 w0 = (u32)f2bf(v.x) | ((u32)f2bf(v.y) << 16);
    u32 w1 = (u32)f2bf(v.z) | ((u32)f2bf(v.w) << 16);
    uint2* dst = (uint2*)(Xg + (size_t)p * DIMSZ + threadIdx.x * 4);
    *dst = make_uint2(w0, w1);
}

// ---------------- grouped GEMM: 128x128 tile, BK=32, 4 waves ----------------
// A: grouped bf16 rows [NTOK][KDIM]; Ball: fp32 [NE][KDIM][NDIM] (converted on the fly)
// EPI==1: H[p*NDIM+col] = bf16(gelu(acc+b1))   EPI==2: out[perm[p]*NDIM+col] = acc+b2
template <int KDIM, int NDIM, int EPI>
__global__ __launch_bounds__(256) void k_gemm(const u16* __restrict__ A,
                                              const float* __restrict__ Ball,
                                              const float* __restrict__ biasAll,
                                              const int* __restrict__ counts,
                                              const int* __restrict__ offs,
                                              const int* __restrict__ perm,
                                              u16* __restrict__ Hout,
                                              float* __restrict__ Fout) {
    // map blockIdx.x -> (expert, local row tile)
    int e = -1, lrt = 0, acc0 = 0;
#pragma unroll
    for (int i = 0; i < NE; i++) {
        int rt = (counts[i] + 127) >> 7;
        if (e < 0 && (int)blockIdx.x < acc0 + rt) { e = i; lrt = (int)blockIdx.x - acc0; }
        acc0 += rt;
    }
    if (e < 0) return;
    int row0 = offs[e] + lrt * 128;
    int nrows = offs[e] + counts[e] - row0;
    if (nrows > 128) nrows = 128;
    int n0 = blockIdx.y * 128;
    const float* B = Ball + (size_t)e * KDIM * NDIM;

    __shared__ u16 As[128][40];  // [row][k], 8-elem pad -> 80B row stride (16B aligned)
    __shared__ u16 Bs[128][40];  // [n][k] (transposed during staging)

    int tid = threadIdx.x;
    int lane = tid & 63;
    int wave = tid >> 6;
    int wr = wave >> 1, wc = wave & 1;

    f32x4 acc[4][4] = {};

    int bn = tid & 127;      // B staging: column n within tile
    int bkg = tid >> 7;      // 0..1 -> k-halves

    for (int kk = 0; kk < KDIM / 32; kk++) {
        __syncthreads();
        // stage A (bf16, vectorized 16B)
#pragma unroll
        for (int pass = 0; pass < 2; pass++) {
            int idx = tid + pass * 256;
            int r = idx >> 2, slot = idx & 3;
            int rc = r < nrows ? r : nrows - 1;
            const uint4* sa = (const uint4*)(A + (size_t)(row0 + rc) * KDIM + kk * 32 + slot * 8);
            *(uint4*)&As[r][slot * 8] = *sa;
        }
        // stage B: 16 k-strided (lane-coalesced) fp32 loads -> bf16 -> Bs[n][k]
        {
            const float* bp = B + (size_t)(kk * 32 + bkg * 16) * NDIM + n0 + bn;
            u32 w[8];
#pragma unroll
            for (int j = 0; j < 8; j++) {
                u16 lo = f2bf(bp[(size_t)(2 * j) * NDIM]);
                u16 hi = f2bf(bp[(size_t)(2 * j + 1) * NDIM]);
                w[j] = (u32)lo | ((u32)hi << 16);
            }
            *(uint4*)&Bs[bn][bkg * 16]     = make_uint4(w[0], w[1], w[2], w[3]);
            *(uint4*)&Bs[bn][bkg * 16 + 8] = make_uint4(w[4], w[5], w[6], w[7]);
        }
        __syncthreads();
        // fragments + MFMA
        bf16x8 af[4], bfr[4];
#pragma unroll
        for (int m = 0; m < 4; m++)
            af[m] = *(const bf16x8*)&As[wr * 64 + m * 16 + (lane & 15)][(lane >> 4) * 8];
#pragma unroll
        for (int n = 0; n < 4; n++)
            bfr[n] = *(const bf16x8*)&Bs[wc * 64 + n * 16 + (lane & 15)][(lane >> 4) * 8];
#pragma unroll
        for (int m = 0; m < 4; m++)
#pragma unroll
            for (int n = 0; n < 4; n++)
                acc[m][n] = __builtin_amdgcn_mfma_f32_16x16x32_bf16(af[m], bfr[n], acc[m][n], 0, 0, 0);
    }

    // epilogue
    int cb = lane & 15;
    int rq = lane >> 4;
#pragma unroll
    for (int m = 0; m < 4; m++) {
        int rbase = wr * 64 + m * 16 + rq * 4;
#pragma unroll
        for (int n = 0; n < 4; n++) {
            int col = n0 + wc * 64 + n * 16 + cb;
            float bias = biasAll[(size_t)e * NDIM + col];
#pragma unroll
            for (int j = 0; j < 4; j++) {
                int r = rbase + j;
                if (r < nrows) {
                    float v = acc[m][n][j] + bias;
                    int p = row0 + r;
                    if (EPI == 1) {
                        float g = 0.5f * v * (1.0f + erff(v * 0.70710678118654752f));
                        Hout[(size_t)p * NDIM + col] = f2bf(g);
                    } else {
                        int trow = perm[p];
                        Fout[(size_t)trow * NDIM + col] = v;
                    }
                }
            }
        }
    }
}

extern "C" void kernel_launch(void* const* d_in, const int* in_sizes, int n_in,
                              void* d_out, int out_size, void* d_ws, size_t ws_size,
                              hipStream_t stream) {
    const float* x  = (const float*)d_in[0];
    const float* Wg = (const float*)d_in[1];
    const float* W1 = (const float*)d_in[2];
    const float* b1 = (const float*)d_in[3];
    const float* W2 = (const float*)d_in[4];
    const float* b2 = (const float*)d_in[5];
    float* out = (float*)d_out;

    char* ws = (char*)d_ws;
    int* ids    = (int*)(ws + 0);          // 16384 B
    int* counts = (int*)(ws + 16384);      // 32 B
    int* offs   = (int*)(ws + 16448);      // 32 B
    int* cursor = (int*)(ws + 16512);      // 32 B
    int* perm   = (int*)(ws + 16576);      // 16384 B
    u16* Xg     = (u16*)(ws + 33024);      // 8 MiB   (4096x1024 bf16)
    u16* H      = (u16*)(ws + 33024 + 8388608);  // 32 MiB (4096x4096 bf16)

    k_init<<<dim3(1), dim3(64), 0, stream>>>(counts, cursor);
    k_router<<<dim3(NTOK / 4), dim3(256), 0, stream>>>(x, Wg, ids, counts);
    k_scan<<<dim3(1), dim3(64), 0, stream>>>(counts, offs);
    k_gather<<<dim3(NTOK), dim3(256), 0, stream>>>(x, ids, offs, cursor, perm, Xg);
    k_gemm<DIMSZ, HID, 1><<<dim3(RT_MAX, HID / 128), dim3(256), 0, stream>>>(
        Xg, W1, b1, counts, offs, perm, H, (float*)nullptr);
    k_gemm<HID, DIMSZ, 2><<<dim3(RT_MAX, DIMSZ / 128), dim3(256), 0, stream>>>(
        H, W2, b2, counts, offs, perm, (u16*)nullptr, out);
}

// Round 2
// 345.178 us; speedup vs baseline: 1.2352x; 1.2352x over previous
//
#include <hip/hip_runtime.h>
#include <hip/hip_bf16.h>
#include <math.h>

#define NTOK 4096
#define DIMSZ 1024
#define HID 4096
#define NE 8
#define RT_MAX 40   // max sum over experts of ceil(count/128) is 39; pad to 40

typedef unsigned short u16;
typedef unsigned int u32;
typedef __attribute__((ext_vector_type(8))) short bf16x8;
typedef __attribute__((ext_vector_type(4))) float f32x4;

static __device__ __forceinline__ u16 f2bf(float f) {
    u32 u = __float_as_uint(f);
    u32 r = u + 0x7fffu + ((u >> 16) & 1u);   // round-to-nearest-even
    return (u16)(r >> 16);
}

static __device__ __forceinline__ u32 pk2bf(float lo, float hi) {
    __hip_bfloat162 h = __float22bfloat162_rn(make_float2(lo, hi));
    return *(u32*)&h;
}

// ---------------- init: zero counts + cursor ----------------
__global__ void k_init(int* counts, int* cursor) {
    if (threadIdx.x < NE) { counts[threadIdx.x] = 0; cursor[threadIdx.x] = 0; }
}

// ---------------- router: fp32 argmax over 8 experts ----------------
__global__ __launch_bounds__(256) void k_router(const float* __restrict__ x,
                                                const float* __restrict__ Wg,
                                                int* __restrict__ ids,
                                                int* __restrict__ counts) {
    int wave = threadIdx.x >> 6;
    int lane = threadIdx.x & 63;
    int t = blockIdx.x * 4 + wave;

    const float4* xr = (const float4*)(x + (size_t)t * DIMSZ);
    float4 xv[4];
#pragma unroll
    for (int j = 0; j < 4; j++) xv[j] = xr[j * 64 + lane];

    float s[NE];
#pragma unroll
    for (int e = 0; e < NE; e++) {
        const float4* wr = (const float4*)(Wg + (size_t)e * DIMSZ);
        float p = 0.f;
#pragma unroll
        for (int j = 0; j < 4; j++) {
            float4 w = wr[j * 64 + lane];
            p += xv[j].x * w.x + xv[j].y * w.y + xv[j].z * w.z + xv[j].w * w.w;
        }
#pragma unroll
        for (int m = 32; m >= 1; m >>= 1) p += __shfl_xor(p, m, 64);
        s[e] = p;
    }
    if (lane == 0) {
        int best = 0;
#pragma unroll
        for (int e = 1; e < NE; e++) if (s[e] > s[best]) best = e;  // first-max tiebreak
        ids[t] = best;
        atomicAdd(&counts[best], 1);
    }
}

// ---------------- scan: exclusive prefix over 8 counts ----------------
__global__ void k_scan(const int* __restrict__ counts, int* __restrict__ offs) {
    if (threadIdx.x == 0) {
        int a = 0;
        for (int e = 0; e < NE; e++) { offs[e] = a; a += counts[e]; }
    }
}

// ---------------- gather: build perm + bf16-convert x into grouped Xg ----------------
__global__ __launch_bounds__(256) void k_gather(const float* __restrict__ x,
                                                const int* __restrict__ ids,
                                                const int* __restrict__ offs,
                                                int* __restrict__ cursor,
                                                int* __restrict__ perm,
                                                u16* __restrict__ Xg) {
    int t = blockIdx.x;
    __shared__ int sp;
    if (threadIdx.x == 0) {
        int e = ids[t];
        int p = offs[e] + atomicAdd(&cursor[e], 1);
        perm[p] = t;
        sp = p;
    }
    __syncthreads();
    int p = sp;
    const float4* src = (const float4*)(x + (size_t)t * DIMSZ);
    float4 v = src[threadIdx.x];
    u32 w0 = pk2bf(v.x, v.y);
    u32 w1 = pk2bf(v.z, v.w);
    uint2* dst = (uint2*)(Xg + (size_t)p * DIMSZ + threadIdx.x * 4);
    *dst = make_uint2(w0, w1);
}

// ---------------- grouped GEMM: 128x128 tile, BK=64, 4 waves ----------------
// A: grouped bf16 rows [NTOK][KDIM] (row-major K).
// Ball: fp32 [NE][KDIM][NDIM] — transposed+converted to bf16 in registers during staging.
// LDS tiles As/Bs are [row][k] with 128B rows, XOR-swizzled: byte ^= ((row&7)<<4).
// A is staged with global_load_lds (linear LDS dest, inverse-swizzled GLOBAL source).
// Grid is 1-D (RT_MAX * NT), XCD-bijective swizzle, x (row-tile) fastest so the
// row-tiles of one (expert, n-stripe) land on one XCD and share the B stripe in L2.
// EPI==1: H[p*NDIM+col] = bf16(gelu(acc+b1))   EPI==2: out[perm[p]*NDIM+col] = acc+b2
template <int KDIM, int NDIM, int EPI>
__global__ __launch_bounds__(256) void k_gemm(const u16* __restrict__ A,
                                              const float* __restrict__ Ball,
                                              const float* __restrict__ biasAll,
                                              const int* __restrict__ counts,
                                              const int* __restrict__ offs,
                                              const int* __restrict__ perm,
                                              u16* __restrict__ Hout,
                                              float* __restrict__ Fout) {
    constexpr int NT = NDIM / 128;
    constexpr int NWG = RT_MAX * NT;   // multiple of 8 for both instantiations
    constexpr int CPX = NWG / 8;
    int bid = blockIdx.x;
    int wid = (bid & 7) * CPX + (bid >> 3);   // bijective XCD swizzle
    int x = wid % RT_MAX;                      // row-tile (fast axis -> same XCD)
    int n0 = (wid / RT_MAX) * 128;             // n-stripe

    // map x -> (expert, local row tile)
    int e = -1, lrt = 0, a0 = 0;
#pragma unroll
    for (int i = 0; i < NE; i++) {
        int rt = (counts[i] + 127) >> 7;
        if (e < 0 && x < a0 + rt) { e = i; lrt = x - a0; }
        a0 += rt;
    }
    if (e < 0) return;
    int row0 = offs[e] + lrt * 128;
    int nrows = offs[e] + counts[e] - row0;
    if (nrows > 128) nrows = 128;

    __shared__ alignas(16) u16 As[128][64];   // [row][k], 128B rows, swizzled
    __shared__ alignas(16) u16 Bs[128][64];   // [n][k],   128B rows, swizzled

    int tid = threadIdx.x;
    int lane = tid & 63;
    int wave = tid >> 6;
    int wr = wave >> 1, wc = wave & 1;

    // --- A staging precompute: granule g = p*256+tid -> LDS row r=g>>3, slot g&7.
    // LDS dest is linear (granule order); swizzle applied by permuting the GLOBAL
    // source k-block: data for slot s comes from k-block s^(r&7).  (rule #21)
    const u16* srcA[4];
#pragma unroll
    for (int p = 0; p < 4; p++) {
        int g = p * 256 + tid;
        int r = g >> 3, slot = g & 7;
        int rc = r < nrows ? r : nrows - 1;
        srcA[p] = A + (size_t)(row0 + rc) * KDIM + ((slot ^ (r & 7)) * 8);
    }
    // --- B staging: thread loads 8 k-rows x 4 consecutive n (dwordx4), converts,
    // packs per-n into 4 u32 (8 k as bf16), ds_write_b128 to swizzled Bs[n][k].
    int bn4 = (tid & 31) * 4;   // base n
    int bkb = tid >> 5;         // k-block 0..7 (8 consecutive k)
    const float* srcB = Ball + (size_t)e * KDIM * NDIM + (size_t)(bkb * 8) * NDIM + n0 + bn4;

    f32x4 acc[4][4] = {};
    int fr = lane & 15, fc = lane >> 4;

    for (int kk = 0; kk < KDIM / 64; kk++) {
        __syncthreads();
        // stage A: 4 x global_load_lds dwordx4 (16B/lane)
#pragma unroll
        for (int p = 0; p < 4; p++) {
            __builtin_amdgcn_global_load_lds(
                (const __attribute__((address_space(1))) void*)(srcA[p] + kk * 64),
                (__attribute__((address_space(3))) void*)((u16*)&As[0][0] + (p * 256 + wave * 64) * 8),
                16, 0, 0);
        }
        // stage B
        {
            const float* bp = srcB + (size_t)kk * 64 * NDIM;
            float4 v[8];
#pragma unroll
            for (int j = 0; j < 8; j++) v[j] = *(const float4*)(bp + (size_t)j * NDIM);
            const float* vf = (const float*)v;
#pragma unroll
            for (int i = 0; i < 4; i++) {
                int N = bn4 + i;
                u32 w0 = pk2bf(vf[0 + i],  vf[4 + i]);
                u32 w1 = pk2bf(vf[8 + i],  vf[12 + i]);
                u32 w2 = pk2bf(vf[16 + i], vf[20 + i]);
                u32 w3 = pk2bf(vf[24 + i], vf[28 + i]);
                u32 off = (u32)(bkb * 16) ^ (u32)((N & 7) << 4);
                *(uint4*)((char*)&Bs[N][0] + off) = make_uint4(w0, w1, w2, w3);
            }
        }
        __syncthreads();
        // fragments + MFMA (2 k-slices of 32)
#pragma unroll
        for (int k2 = 0; k2 < 2; k2++) {
            bf16x8 af[4], bfr[4];
#pragma unroll
            for (int m = 0; m < 4; m++) {
                int r = wr * 64 + m * 16 + fr;
                u32 off = (u32)(k2 * 64 + fc * 16) ^ (u32)((r & 7) << 4);
                af[m] = *(const bf16x8*)((const char*)&As[r][0] + off);
            }
#pragma unroll
            for (int n = 0; n < 4; n++) {
                int N = wc * 64 + n * 16 + fr;
                u32 off = (u32)(k2 * 64 + fc * 16) ^ (u32)((N & 7) << 4);
                bfr[n] = *(const bf16x8*)((const char*)&Bs[N][0] + off);
            }
#pragma unroll
            for (int m = 0; m < 4; m++)
#pragma unroll
                for (int n = 0; n < 4; n++)
                    acc[m][n] = __builtin_amdgcn_mfma_f32_16x16x32_bf16(af[m], bfr[n], acc[m][n], 0, 0, 0);
        }
    }

    // epilogue (C/D layout: col = lane&15, row = (lane>>4)*4 + j)
    int cb = lane & 15;
    int rq = lane >> 4;
#pragma unroll
    for (int m = 0; m < 4; m++) {
        int rbase = wr * 64 + m * 16 + rq * 4;
#pragma unroll
        for (int n = 0; n < 4; n++) {
            int col = n0 + wc * 64 + n * 16 + cb;
            float bias = biasAll[(size_t)e * NDIM + col];
#pragma unroll
            for (int j = 0; j < 4; j++) {
                int r = rbase + j;
                if (r < nrows) {
                    float v = acc[m][n][j] + bias;
                    int p = row0 + r;
                    if (EPI == 1) {
                        float g = 0.5f * v * (1.0f + erff(v * 0.70710678118654752f));
                        Hout[(size_t)p * NDIM + col] = f2bf(g);
                    } else {
                        int trow = perm[p];
                        Fout[(size_t)trow * NDIM + col] = v;
                    }
                }
            }
        }
    }
}

extern "C" void kernel_launch(void* const* d_in, const int* in_sizes, int n_in,
                              void* d_out, int out_size, void* d_ws, size_t ws_size,
                              hipStream_t stream) {
    const float* x  = (const float*)d_in[0];
    const float* Wg = (const float*)d_in[1];
    const float* W1 = (const float*)d_in[2];
    const float* b1 = (const float*)d_in[3];
    const float* W2 = (const float*)d_in[4];
    const float* b2 = (const float*)d_in[5];
    float* out = (float*)d_out;

    char* ws = (char*)d_ws;
    int* ids    = (int*)(ws + 0);          // 16384 B
    int* counts = (int*)(ws + 16384);      // 32 B
    int* offs   = (int*)(ws + 16448);      // 32 B
    int* cursor = (int*)(ws + 16512);      // 32 B
    int* perm   = (int*)(ws + 16576);      // 16384 B
    u16* Xg     = (u16*)(ws + 33024);      // 8 MiB   (4096x1024 bf16)
    u16* H      = (u16*)(ws + 33024 + 8388608);  // 32 MiB (4096x4096 bf16)

    k_init<<<dim3(1), dim3(64), 0, stream>>>(counts, cursor);
    k_router<<<dim3(NTOK / 4), dim3(256), 0, stream>>>(x, Wg, ids, counts);
    k_scan<<<dim3(1), dim3(64), 0, stream>>>(counts, offs);
    k_gather<<<dim3(NTOK), dim3(256), 0, stream>>>(x, ids, offs, cursor, perm, Xg);
    k_gemm<DIMSZ, HID, 1><<<dim3(RT_MAX * (HID / 128)), dim3(256), 0, stream>>>(
        Xg, W1, b1, counts, offs, perm, H, (float*)nullptr);
    k_gemm<HID, DIMSZ, 2><<<dim3(RT_MAX * (DIMSZ / 128)), dim3(256), 0, stream>>>(
        H, W2, b2, counts, offs, perm, (u16*)nullptr, out);
}